// Round 1
// baseline (1008.452 us; speedup 1.0000x reference)
//
#include <hip/hip_runtime.h>
#include <math.h>

#define DV 256
#define NSEQ 1024
#define HHEADS 8
#define VV 32000
#define QKSCALE 0.17677669529663687f  // 1/sqrt(32)

// ---------------- block-wide reduction (256 threads) ----------------
__device__ __forceinline__ void block_reduce_2(float& s, float& s2, float* sh){
  #pragma unroll
  for(int off=32; off>0; off>>=1){
    s  += __shfl_down(s, off);
    s2 += __shfl_down(s2, off);
  }
  int lane = threadIdx.x & 63;
  int w = threadIdx.x >> 6;
  if(lane == 0){ sh[w] = s; sh[4+w] = s2; }
  __syncthreads();
  s  = sh[0]+sh[1]+sh[2]+sh[3];
  s2 = sh[4]+sh[5]+sh[6]+sh[7];
}

// ---------------- embedding + LayerNorm ----------------
__global__ __launch_bounds__(256) void embed_ln_kernel(
    const int* __restrict__ ids, const float* __restrict__ tok, const float* __restrict__ pos,
    const float* __restrict__ g, const float* __restrict__ bt, float* __restrict__ h){
  __shared__ float sh[8];
  int row = blockIdx.x, t = threadIdx.x;
  int n = row & (NSEQ-1);
  int id = ids[row];
  float vv = tok[(long)id*DV + t] + pos[n*DV + t];
  float s = vv, s2 = vv*vv;
  block_reduce_2(s, s2, sh);
  float mean = s * (1.f/DV);
  float var = fmaxf(s2*(1.f/DV) - mean*mean, 0.f);
  float inv = rsqrtf(var + 1e-5f);
  h[row*DV + t] = (vv-mean)*inv*g[t] + bt[t];
}

// ---------------- (residual +) LayerNorm ----------------
__global__ __launch_bounds__(256) void ln_res_kernel(
    const float* __restrict__ x, const float* __restrict__ r,
    float* __restrict__ out, const float* __restrict__ g, const float* __restrict__ bt){
  __shared__ float sh[8];
  int row = blockIdx.x, t = threadIdx.x;
  float vv = x[row*DV + t];
  if(r) vv += r[row*DV + t];
  float s = vv, s2 = vv*vv;
  block_reduce_2(s, s2, sh);
  float mean = s * (1.f/DV);
  float var = fmaxf(s2*(1.f/DV) - mean*mean, 0.f);
  float inv = rsqrtf(var + 1e-5f);
  out[row*DV + t] = (vv-mean)*inv*g[t] + bt[t];
}

// ---------------- tiled f32 GEMM: C[M,N] = A[M,K]@B[K,N] (+bias)(+gelu) ----------------
// 64x64 tile, 256 threads, 4x4 micro-tile, K-step 16. M%64==0, N%64==0, K%16==0.
template<int ACT>
__global__ __launch_bounds__(256) void gemm_kernel(
    const float* __restrict__ A, const float* __restrict__ B, const float* __restrict__ bias,
    float* __restrict__ C, int M, int N, int K){
  __shared__ float As[16][64];
  __shared__ float Bs[16][64];
  int tm = blockIdx.x*64, tn = blockIdx.y*64;
  int t = threadIdx.x;
  int tx = t & 15, ty = t >> 4;
  int ar = t >> 2, ac = (t & 3) * 4;
  int bk = t >> 4, bn = (t & 15) * 4;
  float acc[4][4] = {};
  for(int k0=0; k0<K; k0+=16){
    float4 av = *(const float4*)&A[(long)(tm+ar)*K + k0 + ac];
    float4 bv = *(const float4*)&B[(long)(k0+bk)*N + tn + bn];
    As[ac+0][ar]=av.x; As[ac+1][ar]=av.y; As[ac+2][ar]=av.z; As[ac+3][ar]=av.w;
    *(float4*)&Bs[bk][bn] = bv;
    __syncthreads();
    #pragma unroll
    for(int kk=0; kk<16; kk++){
      float4 a4 = *(const float4*)&As[kk][ty*4];
      float4 b4 = *(const float4*)&Bs[kk][tx*4];
      float aa[4] = {a4.x,a4.y,a4.z,a4.w};
      float bb[4] = {b4.x,b4.y,b4.z,b4.w};
      #pragma unroll
      for(int i=0;i<4;i++)
        #pragma unroll
        for(int j=0;j<4;j++) acc[i][j] += aa[i]*bb[j];
    }
    __syncthreads();
  }
  #pragma unroll
  for(int i=0;i<4;i++){
    int row = tm + ty*4 + i;
    int col = tn + tx*4;
    float4 bsv = bias ? *(const float4*)&bias[col] : make_float4(0.f,0.f,0.f,0.f);
    float xo[4] = {acc[i][0]+bsv.x, acc[i][1]+bsv.y, acc[i][2]+bsv.z, acc[i][3]+bsv.w};
    if(ACT == 1){
      #pragma unroll
      for(int j=0;j<4;j++) xo[j] = 0.5f*xo[j]*(1.f + erff(xo[j]*0.70710678118654752f));
    }
    float4 o = make_float4(xo[0],xo[1],xo[2],xo[3]);
    *(float4*)&C[(long)row*N + col] = o;
  }
}

// ---------------- phase projection -> cos/sin, transposed to (b,h,n) ----------------
__global__ __launch_bounds__(256) void phase_kernel(
    const float* __restrict__ h, const float* __restrict__ pw, const float* __restrict__ pb,
    float* __restrict__ cph, float* __restrict__ sph){
  int t = threadIdx.x;
  int r = blockIdx.x*32 + (t>>3);   // row in [0, B*N)
  int hh = t & 7;
  const float* hr = &h[(long)r*DV];
  float acc = pb[hh];
  #pragma unroll 8
  for(int kk=0; kk<DV; kk++) acc += hr[kk]*pw[kk*HHEADS + hh];
  int b = r >> 10, n = r & 1023;
  float sv, cv;
  __sincosf(acc, &sv, &cv);
  int idx = (b*HHEADS + hh)*NSEQ + n;
  cph[idx] = cv; sph[idx] = sv;
}

// ---------------- flash attention with phase-modulated scores ----------------
// grid: (B*H)*32 blocks; block = 256 threads; 32 query rows x 64-key tiles.
__global__ __launch_bounds__(256) void attn_kernel(
    const float* __restrict__ q, const float* __restrict__ k, const float* __restrict__ v,
    const float* __restrict__ cph, const float* __restrict__ sph, float* __restrict__ msg){
  int bh = blockIdx.x >> 5;
  int it = blockIdx.x & 31;
  int b = bh >> 3, hh = bh & 7;
  int i0 = it * 32;
  __shared__ float qs[32][33];
  __shared__ float ks[64][33];
  __shared__ float vs[64][33];
  __shared__ float ps[32][65];
  __shared__ float cpi[32], spi[32], cpj[64], spj[64];
  int t = threadIdx.x;
  int tx = t & 15, ty = t >> 4;
  {
    int r = t >> 3, c = (t & 7) * 4;
    float4 qv = *(const float4*)&q[(long)(b*NSEQ + i0 + r)*DV + hh*32 + c];
    qs[r][c]=qv.x; qs[r][c+1]=qv.y; qs[r][c+2]=qv.z; qs[r][c+3]=qv.w;
  }
  if(t < 32){ cpi[t] = cph[bh*NSEQ + i0 + t]; spi[t] = sph[bh*NSEQ + i0 + t]; }
  int i_lo = ty*2, i_hi = ty*2+1;
  float m0=-1e30f, m1=-1e30f, l0=0.f, l1=0.f;
  float o00=0.f,o01=0.f,o10=0.f,o11=0.f;
  for(int j0=0; j0<NSEQ; j0+=64){
    __syncthreads();
    {
      int r = t >> 2, c = (t & 3) * 8;
      const float* kp = &k[(long)(b*NSEQ + j0 + r)*DV + hh*32 + c];
      const float* vp = &v[(long)(b*NSEQ + j0 + r)*DV + hh*32 + c];
      float4 k0v = *(const float4*)kp;
      float4 k1v = *(const float4*)(kp+4);
      float4 v0v = *(const float4*)vp;
      float4 v1v = *(const float4*)(vp+4);
      ks[r][c+0]=k0v.x; ks[r][c+1]=k0v.y; ks[r][c+2]=k0v.z; ks[r][c+3]=k0v.w;
      ks[r][c+4]=k1v.x; ks[r][c+5]=k1v.y; ks[r][c+6]=k1v.z; ks[r][c+7]=k1v.w;
      vs[r][c+0]=v0v.x; vs[r][c+1]=v0v.y; vs[r][c+2]=v0v.z; vs[r][c+3]=v0v.w;
      vs[r][c+4]=v1v.x; vs[r][c+5]=v1v.y; vs[r][c+6]=v1v.z; vs[r][c+7]=v1v.w;
    }
    if(t < 64){ cpj[t] = cph[bh*NSEQ + j0 + t]; spj[t] = sph[bh*NSEQ + j0 + t]; }
    __syncthreads();
    // ---- scores: rows i_lo/i_hi, cols tx*4 .. tx*4+3 ----
    float d0[4] = {0,0,0,0}, d1[4] = {0,0,0,0};
    #pragma unroll
    for(int kk=0; kk<32; kk++){
      float a0 = qs[i_lo][kk], a1 = qs[i_hi][kk];
      float b0 = ks[tx*4+0][kk], b1 = ks[tx*4+1][kk];
      float b2 = ks[tx*4+2][kk], b3 = ks[tx*4+3][kk];
      d0[0]+=a0*b0; d0[1]+=a0*b1; d0[2]+=a0*b2; d0[3]+=a0*b3;
      d1[0]+=a1*b0; d1[1]+=a1*b1; d1[2]+=a1*b2; d1[3]+=a1*b3;
    }
    float s0[4], s1r[4];
    float ci0 = cpi[i_lo], si0 = spi[i_lo];
    float ci1 = cpi[i_hi], si1 = spi[i_hi];
    #pragma unroll
    for(int j=0;j<4;j++){
      float cj = cpj[tx*4+j], sj = spj[tx*4+j];
      s0[j]  = d0[j]*QKSCALE*(1.f + ci0*cj + si0*sj)*0.5f;
      s1r[j] = d1[j]*QKSCALE*(1.f + ci1*cj + si1*sj)*0.5f;
    }
    // ---- online softmax over the 64-wide tile (reduce across 16 tx lanes) ----
    float rm0 = fmaxf(fmaxf(s0[0],s0[1]),fmaxf(s0[2],s0[3]));
    float rm1 = fmaxf(fmaxf(s1r[0],s1r[1]),fmaxf(s1r[2],s1r[3]));
    #pragma unroll
    for(int off=1; off<16; off<<=1){
      rm0 = fmaxf(rm0, __shfl_xor(rm0, off));
      rm1 = fmaxf(rm1, __shfl_xor(rm1, off));
    }
    float mn0 = fmaxf(m0, rm0), mn1 = fmaxf(m1, rm1);
    float al0 = __expf(m0 - mn0), al1 = __expf(m1 - mn1);
    float ls0 = 0.f, ls1 = 0.f;
    #pragma unroll
    for(int j=0;j<4;j++){
      float p0 = __expf(s0[j]  - mn0);
      float p1 = __expf(s1r[j] - mn1);
      ps[i_lo][tx*4+j] = p0;
      ps[i_hi][tx*4+j] = p1;
      ls0 += p0; ls1 += p1;
    }
    #pragma unroll
    for(int off=1; off<16; off<<=1){
      ls0 += __shfl_xor(ls0, off);
      ls1 += __shfl_xor(ls1, off);
    }
    l0 = l0*al0 + ls0; l1 = l1*al1 + ls1;
    m0 = mn0; m1 = mn1;
    o00*=al0; o01*=al0; o10*=al1; o11*=al1;
    __syncthreads();
    // ---- PV: o[i][dh], dh = tx*2, tx*2+1 ----
    #pragma unroll 8
    for(int kk=0; kk<64; kk++){
      float a0 = ps[i_lo][kk], a1 = ps[i_hi][kk];
      float c0 = vs[kk][tx*2], c1 = vs[kk][tx*2+1];
      o00 += a0*c0; o01 += a0*c1;
      o10 += a1*c0; o11 += a1*c1;
    }
  }
  float inv0 = 1.f/l0, inv1 = 1.f/l1;
  long orow0 = (long)(b*NSEQ + i0 + i_lo)*DV + hh*32 + tx*2;
  long orow1 = (long)(b*NSEQ + i0 + i_hi)*DV + hh*32 + tx*2;
  msg[orow0] = o00*inv0; msg[orow0+1] = o01*inv0;
  msg[orow1] = o10*inv1; msg[orow1+1] = o11*inv1;
}

// ---------------- mean pool (2 stages) ----------------
__global__ __launch_bounds__(256) void pool1_kernel(const float* __restrict__ x, float* __restrict__ part){
  int t = threadIdx.x;
  int b = blockIdx.x >> 4, c = blockIdx.x & 15;
  long base = (long)(b*NSEQ + c*64)*DV + t;
  float acc = 0.f;
  #pragma unroll 4
  for(int i=0;i<64;i++) acc += x[base + (long)i*DV];
  part[blockIdx.x*DV + t] = acc;
}

__global__ __launch_bounds__(256) void pool2_kernel(const float* __restrict__ part, float* __restrict__ pooled){
  int t = threadIdx.x, b = blockIdx.x;
  float acc = 0.f;
  #pragma unroll
  for(int c=0;c<16;c++) acc += part[(b*16+c)*DV + t];
  pooled[b*DV + t] = acc * (1.f/ (float)NSEQ);
}

// ---------------- head: out[b,v] = pooled[b,:] @ head_w[:,v] + head_b[v] ----------------
__global__ __launch_bounds__(256) void head_kernel(
    const float* __restrict__ pooled, const float* __restrict__ W,
    const float* __restrict__ hb, float* __restrict__ out){
  int vcol = blockIdx.x*256 + threadIdx.x;
  float a0 = 0.f, a1 = 0.f;
  #pragma unroll 8
  for(int d=0; d<DV; d++){
    float w = W[(long)d*VV + vcol];
    a0 += pooled[d]*w;
    a1 += pooled[DV+d]*w;
  }
  float bb = hb[vcol];
  out[vcol] = a0 + bb;
  out[VV + vcol] = a1 + bb;
}

extern "C" void kernel_launch(void* const* d_in, const int* in_sizes, int n_in,
                              void* d_out, int out_size, void* d_ws, size_t ws_size,
                              hipStream_t stream){
  const int*   ids   = (const int*)  d_in[0];
  const float* tok   = (const float*)d_in[1];
  const float* pos   = (const float*)d_in[2];
  const float* en_g  = (const float*)d_in[3];
  const float* en_b  = (const float*)d_in[4];
  // d_in[5], d_in[6]: pi_w, pi_b — phases state never feeds output, skipped
  const float* Wq    = (const float*)d_in[7];
  const float* Wk    = (const float*)d_in[8];
  const float* Wv    = (const float*)d_in[9];
  const float* Wo    = (const float*)d_in[10];
  const float* pp_w  = (const float*)d_in[11];
  const float* pp_b  = (const float*)d_in[12];
  const float* f1_w  = (const float*)d_in[13];
  const float* f1_b  = (const float*)d_in[14];
  const float* f2_w  = (const float*)d_in[15];
  const float* f2_b  = (const float*)d_in[16];
  const float* ln1_g = (const float*)d_in[17];
  const float* ln1_b = (const float*)d_in[18];
  const float* ln2_g = (const float*)d_in[19];
  const float* ln2_b = (const float*)d_in[20];
  // d_in[21], d_in[22]: pu_w, pu_b — skipped (dead)
  const float* on_g  = (const float*)d_in[23];
  const float* on_b  = (const float*)d_in[24];
  const float* head_w= (const float*)d_in[25];
  const float* head_b= (const float*)d_in[26];
  float* out = (float*)d_out;

  float* ws = (float*)d_ws;
  float* h     = ws;                  // 524288
  float* big   = h + 524288;          // 2097152: q/k/v during attention, ff1 during FF
  float* qb    = big;
  float* kb    = big + 524288;
  float* vb    = big + 1048576;
  float* s1    = big + 2097152;       // 524288
  float* s2    = s1 + 524288;         // 524288
  float* cphb  = s2 + 524288;         // 16384
  float* sphb  = cphb + 16384;        // 16384
  float* part  = sphb + 16384;        // 8192
  float* pooled= part + 8192;         // 512

  embed_ln_kernel<<<2048, 256, 0, stream>>>(ids, tok, pos, en_g, en_b, h);

  dim3 g_dd(32, 4);     // M=2048,N=256
  dim3 g_df(32, 16);    // M=2048,N=1024
  for(int tt=0; tt<2; tt++){
    for(int l=0; l<2; l++){
      const float* wq = Wq + l*65536;
      const float* wk = Wk + l*65536;
      const float* wv = Wv + l*65536;
      const float* wo = Wo + l*65536;
      gemm_kernel<0><<<g_dd, 256, 0, stream>>>(h, wq, nullptr, qb, 2048, 256, 256);
      gemm_kernel<0><<<g_dd, 256, 0, stream>>>(h, wk, nullptr, kb, 2048, 256, 256);
      gemm_kernel<0><<<g_dd, 256, 0, stream>>>(h, wv, nullptr, vb, 2048, 256, 256);
      phase_kernel<<<64, 256, 0, stream>>>(h, pp_w + l*(DV*HHEADS), pp_b + l*HHEADS, cphb, sphb);
      attn_kernel<<<512, 256, 0, stream>>>(qb, kb, vb, cphb, sphb, s1);
      gemm_kernel<0><<<g_dd, 256, 0, stream>>>(s1, wo, nullptr, s2, 2048, 256, 256);
      ln_res_kernel<<<2048, 256, 0, stream>>>(s2, h, h, ln1_g + l*DV, ln1_b + l*DV);
      gemm_kernel<1><<<g_df, 256, 0, stream>>>(h, f1_w + l*(DV*1024), f1_b + l*1024, big, 2048, 1024, 256);
      gemm_kernel<0><<<g_dd, 256, 0, stream>>>(big, f2_w + l*(1024*DV), f2_b + l*DV, s2, 2048, 256, 1024);
      ln_res_kernel<<<2048, 256, 0, stream>>>(s2, h, h, ln2_g + l*DV, ln2_b + l*DV);
    }
  }
  ln_res_kernel<<<2048, 256, 0, stream>>>(h, nullptr, s1, on_g, on_b);
  pool1_kernel<<<32, 256, 0, stream>>>(s1, part);
  pool2_kernel<<<2, 256, 0, stream>>>(part, pooled);
  head_kernel<<<125, 256, 0, stream>>>(pooled, head_w, head_b, out);
}

// Round 2
// 595.255 us; speedup vs baseline: 1.6942x; 1.6942x over previous
//
#include <hip/hip_runtime.h>
#include <hip/hip_bf16.h>
#include <math.h>

#define DV 256
#define NSEQ 1024
#define HHEADS 8
#define VV 32000
#define QKSCALE 0.17677669529663687f  // 1/sqrt(32)

typedef __attribute__((ext_vector_type(8))) short short8v;
typedef __attribute__((ext_vector_type(4))) float f32x4;

__device__ __forceinline__ unsigned short f2bf(float f){
  __hip_bfloat16 b = __float2bfloat16(f);
  return *reinterpret_cast<unsigned short*>(&b);
}

// ---------------- weight transpose + f32->bf16 convert (one kernel, all weights) ----------------
// dst layout (bf16): [Wq l0,l1, Wk l0,l1, Wv l0,l1, Wo l0,l1] each 256x256 transposed,
// then f1t 2x(1024x256), then f2t 2x(256x1024). All stored as Wt[n][k].
__global__ __launch_bounds__(256) void transpose_cvt_all(
    const float* __restrict__ Wq, const float* __restrict__ Wk,
    const float* __restrict__ Wv, const float* __restrict__ Wo,
    const float* __restrict__ f1w, const float* __restrict__ f2w,
    __hip_bfloat16* __restrict__ dst){
  __shared__ float sh[32][33];
  int bid = blockIdx.x;
  const float* src; __hip_bfloat16* d; int K, N, tile;
  if(bid < 512){
    int m = bid >> 6;            // 0..7
    int wsel = m >> 1, l = m & 1;
    const float* b01 = wsel ? Wk : Wq;
    const float* b23 = (wsel==2) ? Wv : Wo;
    src = (wsel < 2 ? b01 : b23) + l*65536;
    d = dst + m*65536;
    K = 256; N = 256; tile = bid & 63;
  } else if(bid < 1024){
    int b2 = bid - 512; int m = b2 >> 8;   // 0..1
    src = f1w + m*262144; d = dst + 8*65536 + m*262144;
    K = 256; N = 1024; tile = b2 & 255;
  } else {
    int b2 = bid - 1024; int m = b2 >> 8;
    src = f2w + m*262144; d = dst + 8*65536 + 2*262144 + m*262144;
    K = 1024; N = 256; tile = b2 & 255;
  }
  int ntn = N >> 5;
  int tk = tile / ntn, tn = tile - tk*ntn;
  int k0 = tk*32, n0 = tn*32;
  int t = threadIdx.x;
  {
    int rr = t >> 3, cc = (t & 7) * 4;
    float4 v = *(const float4*)&src[(long)(k0+rr)*N + n0 + cc];
    sh[rr][cc]=v.x; sh[rr][cc+1]=v.y; sh[rr][cc+2]=v.z; sh[rr][cc+3]=v.w;
  }
  __syncthreads();
  int nn = t >> 3, kk = (t & 7) * 4;
  ushort4 o;
  o.x = f2bf(sh[kk+0][nn]);
  o.y = f2bf(sh[kk+1][nn]);
  o.z = f2bf(sh[kk+2][nn]);
  o.w = f2bf(sh[kk+3][nn]);
  *(ushort4*)&((unsigned short*)d)[(long)(n0+nn)*K + k0 + kk] = o;
}

// ---------------- embedding + LayerNorm (wave-per-row), writes f32 + bf16 ----------------
__global__ __launch_bounds__(256) void embed_ln_kernel(
    const int* __restrict__ ids, const float* __restrict__ tok, const float* __restrict__ pos,
    const float* __restrict__ g, const float* __restrict__ bt,
    float* __restrict__ h, __hip_bfloat16* __restrict__ hb){
  int t = threadIdx.x;
  int lane = t & 63;
  int row = blockIdx.x*4 + (t >> 6);
  int n = row & (NSEQ-1);
  int id = ids[row];
  float4 vv = ((const float4*)tok)[(long)id*64 + lane];
  float4 pv = ((const float4*)pos)[n*64 + lane];
  vv.x += pv.x; vv.y += pv.y; vv.z += pv.z; vv.w += pv.w;
  float s  = vv.x+vv.y+vv.z+vv.w;
  float s2 = vv.x*vv.x+vv.y*vv.y+vv.z*vv.z+vv.w*vv.w;
  #pragma unroll
  for(int off=1; off<64; off<<=1){ s += __shfl_xor(s, off); s2 += __shfl_xor(s2, off); }
  float mean = s*(1.f/DV);
  float var = fmaxf(s2*(1.f/DV) - mean*mean, 0.f);
  float inv = rsqrtf(var + 1e-5f);
  float4 gv = ((const float4*)g)[lane];
  float4 bv = ((const float4*)bt)[lane];
  float4 o;
  o.x=(vv.x-mean)*inv*gv.x+bv.x; o.y=(vv.y-mean)*inv*gv.y+bv.y;
  o.z=(vv.z-mean)*inv*gv.z+bv.z; o.w=(vv.w-mean)*inv*gv.w+bv.w;
  ((float4*)h)[row*64 + lane] = o;
  ushort4 ob; ob.x=f2bf(o.x); ob.y=f2bf(o.y); ob.z=f2bf(o.z); ob.w=f2bf(o.w);
  *(ushort4*)&hb[row*DV + lane*4] = ob;
}

// ---------------- (residual +) LayerNorm (wave-per-row), writes f32 + optional bf16 ----------------
__global__ __launch_bounds__(256) void ln_res_kernel(
    const float* __restrict__ x, const float* __restrict__ r,
    float* __restrict__ out, __hip_bfloat16* __restrict__ outb,
    const float* __restrict__ g, const float* __restrict__ bt){
  int t = threadIdx.x;
  int lane = t & 63;
  int row = blockIdx.x*4 + (t >> 6);
  float4 vv = ((const float4*)x)[row*64 + lane];
  if(r){
    float4 rv = ((const float4*)r)[row*64 + lane];
    vv.x += rv.x; vv.y += rv.y; vv.z += rv.z; vv.w += rv.w;
  }
  float s  = vv.x+vv.y+vv.z+vv.w;
  float s2 = vv.x*vv.x+vv.y*vv.y+vv.z*vv.z+vv.w*vv.w;
  #pragma unroll
  for(int off=1; off<64; off<<=1){ s += __shfl_xor(s, off); s2 += __shfl_xor(s2, off); }
  float mean = s*(1.f/DV);
  float var = fmaxf(s2*(1.f/DV) - mean*mean, 0.f);
  float inv = rsqrtf(var + 1e-5f);
  float4 gv = ((const float4*)g)[lane];
  float4 bv = ((const float4*)bt)[lane];
  float4 o;
  o.x=(vv.x-mean)*inv*gv.x+bv.x; o.y=(vv.y-mean)*inv*gv.y+bv.y;
  o.z=(vv.z-mean)*inv*gv.z+bv.z; o.w=(vv.w-mean)*inv*gv.w+bv.w;
  ((float4*)out)[row*64 + lane] = o;
  if(outb){
    ushort4 ob; ob.x=f2bf(o.x); ob.y=f2bf(o.y); ob.z=f2bf(o.z); ob.w=f2bf(o.w);
    *(ushort4*)&outb[row*DV + lane*4] = ob;
  }
}

// ---------------- bf16 MFMA GEMM: C[M,N] = A[M,K] @ Bt[N,K]^T (+bias)(+gelu) ----------------
// 64x64 tile, 4 waves (2x2), each wave 32x32 via 2x2 frags of 16x16x32. K%64==0.
template<int ACT, int OUT_BF16>
__global__ __launch_bounds__(256) void mfma_gemm(
    const __hip_bfloat16* __restrict__ A, const __hip_bfloat16* __restrict__ Bt,
    const float* __restrict__ bias, void* __restrict__ Cout, int M, int N, int K){
  __shared__ short As[64][72];
  __shared__ short Bs[64][72];
  int tm = blockIdx.x*64, tn = blockIdx.y*64;
  int t = threadIdx.x;
  int lane = t & 63, w = t >> 6;
  int wm = w >> 1, wn = w & 1;
  f32x4 acc[2][2] = {};
  int srow = t >> 2, sk = (t & 3) * 16;
  const short* gA = (const short*)A;
  const short* gB = (const short*)Bt;
  int lr = lane & 15, lk = (lane >> 4) * 8;
  for(int k0=0; k0<K; k0+=64){
    const short* ga = &gA[(long)(tm+srow)*K + k0 + sk];
    const short* gb = &gB[(long)(tn+srow)*K + k0 + sk];
    short8v a0 = *(const short8v*)ga;
    short8v a1 = *(const short8v*)(ga+8);
    short8v b0 = *(const short8v*)gb;
    short8v b1 = *(const short8v*)(gb+8);
    __syncthreads();
    *(short8v*)&As[srow][sk]   = a0;
    *(short8v*)&As[srow][sk+8] = a1;
    *(short8v*)&Bs[srow][sk]   = b0;
    *(short8v*)&Bs[srow][sk+8] = b1;
    __syncthreads();
    #pragma unroll
    for(int kk=0; kk<2; kk++){
      short8v af0 = *(const short8v*)&As[wm*32 + lr][kk*32 + lk];
      short8v af1 = *(const short8v*)&As[wm*32 + 16 + lr][kk*32 + lk];
      short8v bf0 = *(const short8v*)&Bs[wn*32 + lr][kk*32 + lk];
      short8v bf1 = *(const short8v*)&Bs[wn*32 + 16 + lr][kk*32 + lk];
      acc[0][0] = __builtin_amdgcn_mfma_f32_16x16x32_bf16(af0, bf0, acc[0][0], 0,0,0);
      acc[0][1] = __builtin_amdgcn_mfma_f32_16x16x32_bf16(af0, bf1, acc[0][1], 0,0,0);
      acc[1][0] = __builtin_amdgcn_mfma_f32_16x16x32_bf16(af1, bf0, acc[1][0], 0,0,0);
      acc[1][1] = __builtin_amdgcn_mfma_f32_16x16x32_bf16(af1, bf1, acc[1][1], 0,0,0);
    }
  }
  int lq = lane >> 4;
  #pragma unroll
  for(int fn=0; fn<2; fn++){
    int col = tn + wn*32 + fn*16 + lr;
    float bs = bias ? bias[col] : 0.f;
    #pragma unroll
    for(int fm=0; fm<2; fm++){
      int row0 = tm + wm*32 + fm*16 + lq*4;
      #pragma unroll
      for(int r2=0; r2<4; r2++){
        float xx = acc[fm][fn][r2] + bs;
        if(ACT == 1) xx = 0.5f*xx*(1.f + erff(xx*0.70710678118654752f));
        long idx = (long)(row0+r2)*N + col;
        if(OUT_BF16) ((__hip_bfloat16*)Cout)[idx] = __float2bfloat16(xx);
        else         ((float*)Cout)[idx] = xx;
      }
    }
  }
}

// ---------------- phase projection -> cos/sin, transposed to (b,h,n) ----------------
__global__ __launch_bounds__(256) void phase_kernel(
    const float* __restrict__ h, const float* __restrict__ pw, const float* __restrict__ pb,
    float* __restrict__ cph, float* __restrict__ sph){
  int t = threadIdx.x;
  int r = blockIdx.x*32 + (t>>3);   // row in [0, B*N)
  int hh = t & 7;
  const float* hr = &h[(long)r*DV];
  float acc = pb[hh];
  #pragma unroll 8
  for(int kk=0; kk<DV; kk++) acc += hr[kk]*pw[kk*HHEADS + hh];
  int b = r >> 10, n = r & 1023;
  float sv, cv;
  __sincosf(acc, &sv, &cv);
  int idx = (b*HHEADS + hh)*NSEQ + n;
  cph[idx] = cv; sph[idx] = sv;
}

// ---------------- flash attention with phase-modulated scores (f32, bf16 output) ----------------
__global__ __launch_bounds__(256) void attn_kernel(
    const float* __restrict__ q, const float* __restrict__ k, const float* __restrict__ v,
    const float* __restrict__ cph, const float* __restrict__ sph,
    __hip_bfloat16* __restrict__ msg){
  int bh = blockIdx.x >> 5;
  int it = blockIdx.x & 31;
  int b = bh >> 3, hh = bh & 7;
  int i0 = it * 32;
  __shared__ float qs[32][33];
  __shared__ float ks[64][33];
  __shared__ float vs[64][33];
  __shared__ float ps[32][65];
  __shared__ float cpi[32], spi[32], cpj[64], spj[64];
  int t = threadIdx.x;
  int tx = t & 15, ty = t >> 4;
  {
    int r = t >> 3, c = (t & 7) * 4;
    float4 qv = *(const float4*)&q[(long)(b*NSEQ + i0 + r)*DV + hh*32 + c];
    qs[r][c]=qv.x; qs[r][c+1]=qv.y; qs[r][c+2]=qv.z; qs[r][c+3]=qv.w;
  }
  if(t < 32){ cpi[t] = cph[bh*NSEQ + i0 + t]; spi[t] = sph[bh*NSEQ + i0 + t]; }
  int i_lo = ty*2, i_hi = ty*2+1;
  float m0=-1e30f, m1=-1e30f, l0=0.f, l1=0.f;
  float o00=0.f,o01=0.f,o10=0.f,o11=0.f;
  for(int j0=0; j0<NSEQ; j0+=64){
    __syncthreads();
    {
      int r = t >> 2, c = (t & 3) * 8;
      const float* kp = &k[(long)(b*NSEQ + j0 + r)*DV + hh*32 + c];
      const float* vp = &v[(long)(b*NSEQ + j0 + r)*DV + hh*32 + c];
      float4 k0v = *(const float4*)kp;
      float4 k1v = *(const float4*)(kp+4);
      float4 v0v = *(const float4*)vp;
      float4 v1v = *(const float4*)(vp+4);
      ks[r][c+0]=k0v.x; ks[r][c+1]=k0v.y; ks[r][c+2]=k0v.z; ks[r][c+3]=k0v.w;
      ks[r][c+4]=k1v.x; ks[r][c+5]=k1v.y; ks[r][c+6]=k1v.z; ks[r][c+7]=k1v.w;
      vs[r][c+0]=v0v.x; vs[r][c+1]=v0v.y; vs[r][c+2]=v0v.z; vs[r][c+3]=v0v.w;
      vs[r][c+4]=v1v.x; vs[r][c+5]=v1v.y; vs[r][c+6]=v1v.z; vs[r][c+7]=v1v.w;
    }
    if(t < 64){ cpj[t] = cph[bh*NSEQ + j0 + t]; spj[t] = sph[bh*NSEQ + j0 + t]; }
    __syncthreads();
    float d0[4] = {0,0,0,0}, d1[4] = {0,0,0,0};
    #pragma unroll
    for(int kk=0; kk<32; kk++){
      float a0 = qs[i_lo][kk], a1 = qs[i_hi][kk];
      float b0 = ks[tx*4+0][kk], b1 = ks[tx*4+1][kk];
      float b2 = ks[tx*4+2][kk], b3 = ks[tx*4+3][kk];
      d0[0]+=a0*b0; d0[1]+=a0*b1; d0[2]+=a0*b2; d0[3]+=a0*b3;
      d1[0]+=a1*b0; d1[1]+=a1*b1; d1[2]+=a1*b2; d1[3]+=a1*b3;
    }
    float s0[4], s1r[4];
    float ci0 = cpi[i_lo], si0 = spi[i_lo];
    float ci1 = cpi[i_hi], si1 = spi[i_hi];
    #pragma unroll
    for(int j=0;j<4;j++){
      float cj = cpj[tx*4+j], sj = spj[tx*4+j];
      s0[j]  = d0[j]*QKSCALE*(1.f + ci0*cj + si0*sj)*0.5f;
      s1r[j] = d1[j]*QKSCALE*(1.f + ci1*cj + si1*sj)*0.5f;
    }
    float rm0 = fmaxf(fmaxf(s0[0],s0[1]),fmaxf(s0[2],s0[3]));
    float rm1 = fmaxf(fmaxf(s1r[0],s1r[1]),fmaxf(s1r[2],s1r[3]));
    #pragma unroll
    for(int off=1; off<16; off<<=1){
      rm0 = fmaxf(rm0, __shfl_xor(rm0, off));
      rm1 = fmaxf(rm1, __shfl_xor(rm1, off));
    }
    float mn0 = fmaxf(m0, rm0), mn1 = fmaxf(m1, rm1);
    float al0 = __expf(m0 - mn0), al1 = __expf(m1 - mn1);
    float ls0 = 0.f, ls1 = 0.f;
    #pragma unroll
    for(int j=0;j<4;j++){
      float p0 = __expf(s0[j]  - mn0);
      float p1 = __expf(s1r[j] - mn1);
      ps[i_lo][tx*4+j] = p0;
      ps[i_hi][tx*4+j] = p1;
      ls0 += p0; ls1 += p1;
    }
    #pragma unroll
    for(int off=1; off<16; off<<=1){
      ls0 += __shfl_xor(ls0, off);
      ls1 += __shfl_xor(ls1, off);
    }
    l0 = l0*al0 + ls0; l1 = l1*al1 + ls1;
    m0 = mn0; m1 = mn1;
    o00*=al0; o01*=al0; o10*=al1; o11*=al1;
    __syncthreads();
    #pragma unroll 8
    for(int kk=0; kk<64; kk++){
      float a0 = ps[i_lo][kk], a1 = ps[i_hi][kk];
      float c0 = vs[kk][tx*2], c1 = vs[kk][tx*2+1];
      o00 += a0*c0; o01 += a0*c1;
      o10 += a1*c0; o11 += a1*c1;
    }
  }
  float inv0 = 1.f/l0, inv1 = 1.f/l1;
  long orow0 = (long)(b*NSEQ + i0 + i_lo)*DV + hh*32 + tx*2;
  long orow1 = (long)(b*NSEQ + i0 + i_hi)*DV + hh*32 + tx*2;
  msg[orow0]   = __float2bfloat16(o00*inv0);
  msg[orow0+1] = __float2bfloat16(o01*inv0);
  msg[orow1]   = __float2bfloat16(o10*inv1);
  msg[orow1+1] = __float2bfloat16(o11*inv1);
}

// ---------------- mean pool (2 stages) ----------------
__global__ __launch_bounds__(256) void pool1_kernel(const float* __restrict__ x, float* __restrict__ part){
  int t = threadIdx.x;
  int b = blockIdx.x >> 4, c = blockIdx.x & 15;
  long base = (long)(b*NSEQ + c*64)*DV + t;
  float acc = 0.f;
  #pragma unroll 4
  for(int i=0;i<64;i++) acc += x[base + (long)i*DV];
  part[blockIdx.x*DV + t] = acc;
}

__global__ __launch_bounds__(256) void pool2_kernel(const float* __restrict__ part, float* __restrict__ pooled){
  int t = threadIdx.x, b = blockIdx.x;
  float acc = 0.f;
  #pragma unroll
  for(int c=0;c<16;c++) acc += part[(b*16+c)*DV + t];
  pooled[b*DV + t] = acc * (1.f/ (float)NSEQ);
}

// ---------------- head ----------------
__global__ __launch_bounds__(256) void head_kernel(
    const float* __restrict__ pooled, const float* __restrict__ W,
    const float* __restrict__ hb, float* __restrict__ out){
  int vcol = blockIdx.x*256 + threadIdx.x;
  float a0 = 0.f, a1 = 0.f;
  #pragma unroll 8
  for(int d=0; d<DV; d++){
    float w = W[(long)d*VV + vcol];
    a0 += pooled[d]*w;
    a1 += pooled[DV+d]*w;
  }
  float bb = hb[vcol];
  out[vcol] = a0 + bb;
  out[VV + vcol] = a1 + bb;
}

extern "C" void kernel_launch(void* const* d_in, const int* in_sizes, int n_in,
                              void* d_out, int out_size, void* d_ws, size_t ws_size,
                              hipStream_t stream){
  const int*   ids   = (const int*)  d_in[0];
  const float* tok   = (const float*)d_in[1];
  const float* pos   = (const float*)d_in[2];
  const float* en_g  = (const float*)d_in[3];
  const float* en_b  = (const float*)d_in[4];
  const float* Wq    = (const float*)d_in[7];
  const float* Wk    = (const float*)d_in[8];
  const float* Wv    = (const float*)d_in[9];
  const float* Wo    = (const float*)d_in[10];
  const float* pp_w  = (const float*)d_in[11];
  const float* pp_b  = (const float*)d_in[12];
  const float* f1_b  = (const float*)d_in[14];
  const float* f1_w  = (const float*)d_in[13];
  const float* f2_w  = (const float*)d_in[15];
  const float* f2_b  = (const float*)d_in[16];
  const float* ln1_g = (const float*)d_in[17];
  const float* ln1_b = (const float*)d_in[18];
  const float* ln2_g = (const float*)d_in[19];
  const float* ln2_b = (const float*)d_in[20];
  const float* on_g  = (const float*)d_in[23];
  const float* on_b  = (const float*)d_in[24];
  const float* head_w= (const float*)d_in[25];
  const float* head_b= (const float*)d_in[26];
  float* out = (float*)d_out;

  char* wsb = (char*)d_ws;
  float* h    = (float*)(wsb);                         // 2 MB
  float* s2   = (float*)(wsb + (2u<<20));              // 2 MB
  float* qb   = (float*)(wsb + (4u<<20));              // 2 MB  (union with ff)
  float* kb   = (float*)(wsb + (6u<<20));              // 2 MB
  float* vb   = (float*)(wsb + (8u<<20));              // 2 MB
  __hip_bfloat16* ff   = (__hip_bfloat16*)(wsb + (4u<<20));   // 4 MB (overlays qb/kb)
  __hip_bfloat16* hb   = (__hip_bfloat16*)(wsb + (10u<<20));  // 1 MB
  __hip_bfloat16* msgb = (__hip_bfloat16*)(wsb + (11u<<20));  // 1 MB
  float* cphb = (float*)(wsb + (12u<<20));             // 64 KB
  float* sphb = cphb + 16384;                          // 64 KB
  float* part = sphb + 16384;                          // 32 KB
  float* pooled = part + 8192;                         // 2 KB
  __hip_bfloat16* wt = (__hip_bfloat16*)(wsb + (12u<<20) + (256u<<10)); // 3 MB
  __hip_bfloat16* wqt = wt;
  __hip_bfloat16* wkt = wt + 2*65536;
  __hip_bfloat16* wvt = wt + 4*65536;
  __hip_bfloat16* wot = wt + 6*65536;
  __hip_bfloat16* f1t = wt + 8*65536;
  __hip_bfloat16* f2t = f1t + 2*262144;

  transpose_cvt_all<<<1536, 256, 0, stream>>>(Wq, Wk, Wv, Wo, f1_w, f2_w, wt);
  embed_ln_kernel<<<512, 256, 0, stream>>>(ids, tok, pos, en_g, en_b, h, hb);

  dim3 g_dd(32, 4);
  dim3 g_df(32, 16);
  for(int tt=0; tt<2; tt++){
    for(int l=0; l<2; l++){
      mfma_gemm<0,0><<<g_dd, 256, 0, stream>>>(hb, wqt + l*65536, nullptr, qb, 2048, 256, 256);
      mfma_gemm<0,0><<<g_dd, 256, 0, stream>>>(hb, wkt + l*65536, nullptr, kb, 2048, 256, 256);
      mfma_gemm<0,0><<<g_dd, 256, 0, stream>>>(hb, wvt + l*65536, nullptr, vb, 2048, 256, 256);
      phase_kernel<<<64, 256, 0, stream>>>(h, pp_w + l*(DV*HHEADS), pp_b + l*HHEADS, cphb, sphb);
      attn_kernel<<<512, 256, 0, stream>>>(qb, kb, vb, cphb, sphb, msgb);
      mfma_gemm<0,0><<<g_dd, 256, 0, stream>>>(msgb, wot + l*65536, nullptr, s2, 2048, 256, 256);
      ln_res_kernel<<<512, 256, 0, stream>>>(s2, h, h, hb, ln1_g + l*DV, ln1_b + l*DV);
      mfma_gemm<1,1><<<g_df, 256, 0, stream>>>(hb, f1t + l*262144, f1_b + l*1024, ff, 2048, 1024, 256);
      mfma_gemm<0,0><<<g_dd, 256, 0, stream>>>(ff, f2t + l*262144, f2_b + l*DV, s2, 2048, 256, 1024);
      ln_res_kernel<<<512, 256, 0, stream>>>(s2, h, h, hb, ln2_g + l*DV, ln2_b + l*DV);
    }
  }
  ln_res_kernel<<<512, 256, 0, stream>>>(h, nullptr, s2, nullptr, on_g, on_b);
  pool1_kernel<<<32, 256, 0, stream>>>(s2, part);
  pool2_kernel<<<2, 256, 0, stream>>>(part, pooled);
  head_kernel<<<125, 256, 0, stream>>>(pooled, head_w, head_b, out);
}

// Round 3
// 361.202 us; speedup vs baseline: 2.7919x; 1.6480x over previous
//
#include <hip/hip_runtime.h>
#include <hip/hip_bf16.h>
#include <math.h>

#define DV 256
#define NSEQ 1024
#define HHEADS 8
#define VV 32000
#define QKSCALE 0.17677669529663687f  // 1/sqrt(32)

typedef __attribute__((ext_vector_type(8))) short short8v;
typedef __attribute__((ext_vector_type(4))) float f32x4;

__device__ __forceinline__ unsigned short f2bf(float f){
  __hip_bfloat16 b = __float2bfloat16(f);
  return *reinterpret_cast<unsigned short*>(&b);
}
__device__ __forceinline__ float bfbits2f(unsigned short u){
  unsigned int x = ((unsigned int)u) << 16;
  return __uint_as_float(x);
}

// ---------------- weight transpose + f32->bf16 convert ----------------
__global__ __launch_bounds__(256) void transpose_cvt_all(
    const float* __restrict__ Wq, const float* __restrict__ Wk,
    const float* __restrict__ Wv, const float* __restrict__ Wo,
    const float* __restrict__ f1w, const float* __restrict__ f2w,
    __hip_bfloat16* __restrict__ dst){
  __shared__ float sh[32][33];
  int bid = blockIdx.x;
  const float* src; __hip_bfloat16* d; int K, N, tile;
  if(bid < 512){
    int m = bid >> 6;
    int wsel = m >> 1, l = m & 1;
    const float* b01 = wsel ? Wk : Wq;
    const float* b23 = (wsel==2) ? Wv : Wo;
    src = (wsel < 2 ? b01 : b23) + l*65536;
    d = dst + m*65536;
    K = 256; N = 256; tile = bid & 63;
  } else if(bid < 1024){
    int b2 = bid - 512; int m = b2 >> 8;
    src = f1w + m*262144; d = dst + 8*65536 + m*262144;
    K = 256; N = 1024; tile = b2 & 255;
  } else {
    int b2 = bid - 1024; int m = b2 >> 8;
    src = f2w + m*262144; d = dst + 8*65536 + 2*262144 + m*262144;
    K = 1024; N = 256; tile = b2 & 255;
  }
  int ntn = N >> 5;
  int tk = tile / ntn, tn = tile - tk*ntn;
  int k0 = tk*32, n0 = tn*32;
  int t = threadIdx.x;
  {
    int rr = t >> 3, cc = (t & 7) * 4;
    float4 v = *(const float4*)&src[(long)(k0+rr)*N + n0 + cc];
    sh[rr][cc]=v.x; sh[rr][cc+1]=v.y; sh[rr][cc+2]=v.z; sh[rr][cc+3]=v.w;
  }
  __syncthreads();
  int nn = t >> 3, kk = (t & 7) * 4;
  ushort4 o;
  o.x = f2bf(sh[kk+0][nn]);
  o.y = f2bf(sh[kk+1][nn]);
  o.z = f2bf(sh[kk+2][nn]);
  o.w = f2bf(sh[kk+3][nn]);
  *(ushort4*)&((unsigned short*)d)[(long)(n0+nn)*K + k0 + kk] = o;
}

// ---------------- embedding + LayerNorm ----------------
__global__ __launch_bounds__(256) void embed_ln_kernel(
    const int* __restrict__ ids, const float* __restrict__ tok, const float* __restrict__ pos,
    const float* __restrict__ g, const float* __restrict__ bt,
    float* __restrict__ h, __hip_bfloat16* __restrict__ hb){
  int t = threadIdx.x;
  int lane = t & 63;
  int row = blockIdx.x*4 + (t >> 6);
  int n = row & (NSEQ-1);
  int id = ids[row];
  float4 vv = ((const float4*)tok)[(long)id*64 + lane];
  float4 pv = ((const float4*)pos)[n*64 + lane];
  vv.x += pv.x; vv.y += pv.y; vv.z += pv.z; vv.w += pv.w;
  float s  = vv.x+vv.y+vv.z+vv.w;
  float s2 = vv.x*vv.x+vv.y*vv.y+vv.z*vv.z+vv.w*vv.w;
  #pragma unroll
  for(int off=1; off<64; off<<=1){ s += __shfl_xor(s, off); s2 += __shfl_xor(s2, off); }
  float mean = s*(1.f/DV);
  float var = fmaxf(s2*(1.f/DV) - mean*mean, 0.f);
  float inv = rsqrtf(var + 1e-5f);
  float4 gv = ((const float4*)g)[lane];
  float4 bv = ((const float4*)bt)[lane];
  float4 o;
  o.x=(vv.x-mean)*inv*gv.x+bv.x; o.y=(vv.y-mean)*inv*gv.y+bv.y;
  o.z=(vv.z-mean)*inv*gv.z+bv.z; o.w=(vv.w-mean)*inv*gv.w+bv.w;
  ((float4*)h)[row*64 + lane] = o;
  ushort4 ob; ob.x=f2bf(o.x); ob.y=f2bf(o.y); ob.z=f2bf(o.z); ob.w=f2bf(o.w);
  *(ushort4*)&hb[row*DV + lane*4] = ob;
}

// ---------------- (residual +) LayerNorm ----------------
__global__ __launch_bounds__(256) void ln_res_kernel(
    const float* __restrict__ x, const float* __restrict__ r,
    float* __restrict__ out, __hip_bfloat16* __restrict__ outb,
    const float* __restrict__ g, const float* __restrict__ bt){
  int t = threadIdx.x;
  int lane = t & 63;
  int row = blockIdx.x*4 + (t >> 6);
  float4 vv = ((const float4*)x)[row*64 + lane];
  if(r){
    float4 rv = ((const float4*)r)[row*64 + lane];
    vv.x += rv.x; vv.y += rv.y; vv.z += rv.z; vv.w += rv.w;
  }
  float s  = vv.x+vv.y+vv.z+vv.w;
  float s2 = vv.x*vv.x+vv.y*vv.y+vv.z*vv.z+vv.w*vv.w;
  #pragma unroll
  for(int off=1; off<64; off<<=1){ s += __shfl_xor(s, off); s2 += __shfl_xor(s2, off); }
  float mean = s*(1.f/DV);
  float var = fmaxf(s2*(1.f/DV) - mean*mean, 0.f);
  float inv = rsqrtf(var + 1e-5f);
  float4 gv = ((const float4*)g)[lane];
  float4 bv = ((const float4*)bt)[lane];
  float4 o;
  o.x=(vv.x-mean)*inv*gv.x+bv.x; o.y=(vv.y-mean)*inv*gv.y+bv.y;
  o.z=(vv.z-mean)*inv*gv.z+bv.z; o.w=(vv.w-mean)*inv*gv.w+bv.w;
  ((float4*)out)[row*64 + lane] = o;
  if(outb){
    ushort4 ob; ob.x=f2bf(o.x); ob.y=f2bf(o.y); ob.z=f2bf(o.z); ob.w=f2bf(o.w);
    *(ushort4*)&outb[row*DV + lane*4] = ob;
  }
}

// ---------------- bf16 MFMA GEMM ----------------
template<int ACT, int OUT_BF16>
__global__ __launch_bounds__(256) void mfma_gemm(
    const __hip_bfloat16* __restrict__ A, const __hip_bfloat16* __restrict__ Bt,
    const float* __restrict__ bias, void* __restrict__ Cout, int M, int N, int K){
  __shared__ short As[64][72];
  __shared__ short Bs[64][72];
  int tm = blockIdx.x*64, tn = blockIdx.y*64;
  int t = threadIdx.x;
  int lane = t & 63, w = t >> 6;
  int wm = w >> 1, wn = w & 1;
  f32x4 acc[2][2] = {};
  int srow = t >> 2, sk = (t & 3) * 16;
  const short* gA = (const short*)A;
  const short* gB = (const short*)Bt;
  int lr = lane & 15, lk = (lane >> 4) * 8;
  for(int k0=0; k0<K; k0+=64){
    const short* ga = &gA[(long)(tm+srow)*K + k0 + sk];
    const short* gb = &gB[(long)(tn+srow)*K + k0 + sk];
    short8v a0 = *(const short8v*)ga;
    short8v a1 = *(const short8v*)(ga+8);
    short8v b0 = *(const short8v*)gb;
    short8v b1 = *(const short8v*)(gb+8);
    __syncthreads();
    *(short8v*)&As[srow][sk]   = a0;
    *(short8v*)&As[srow][sk+8] = a1;
    *(short8v*)&Bs[srow][sk]   = b0;
    *(short8v*)&Bs[srow][sk+8] = b1;
    __syncthreads();
    #pragma unroll
    for(int kk=0; kk<2; kk++){
      short8v af0 = *(const short8v*)&As[wm*32 + lr][kk*32 + lk];
      short8v af1 = *(const short8v*)&As[wm*32 + 16 + lr][kk*32 + lk];
      short8v bf0 = *(const short8v*)&Bs[wn*32 + lr][kk*32 + lk];
      short8v bf1 = *(const short8v*)&Bs[wn*32 + 16 + lr][kk*32 + lk];
      acc[0][0] = __builtin_amdgcn_mfma_f32_16x16x32_bf16(af0, bf0, acc[0][0], 0,0,0);
      acc[0][1] = __builtin_amdgcn_mfma_f32_16x16x32_bf16(af0, bf1, acc[0][1], 0,0,0);
      acc[1][0] = __builtin_amdgcn_mfma_f32_16x16x32_bf16(af1, bf0, acc[1][0], 0,0,0);
      acc[1][1] = __builtin_amdgcn_mfma_f32_16x16x32_bf16(af1, bf1, acc[1][1], 0,0,0);
    }
  }
  int lq = lane >> 4;
  #pragma unroll
  for(int fn=0; fn<2; fn++){
    int col = tn + wn*32 + fn*16 + lr;
    float bs = bias ? bias[col] : 0.f;
    #pragma unroll
    for(int fm=0; fm<2; fm++){
      int row0 = tm + wm*32 + fm*16 + lq*4;
      #pragma unroll
      for(int r2=0; r2<4; r2++){
        float xx = acc[fm][fn][r2] + bs;
        if(ACT == 1) xx = 0.5f*xx*(1.f + erff(xx*0.70710678118654752f));
        long idx = (long)(row0+r2)*N + col;
        if(OUT_BF16) ((__hip_bfloat16*)Cout)[idx] = __float2bfloat16(xx);
        else         ((float*)Cout)[idx] = xx;
      }
    }
  }
}

// ---------------- phase projection -> cos/sin, (b,h,n) ----------------
__global__ __launch_bounds__(256) void phase_kernel(
    const float* __restrict__ h, const float* __restrict__ pw, const float* __restrict__ pb,
    float* __restrict__ cph, float* __restrict__ sph){
  int t = threadIdx.x;
  int r = blockIdx.x*32 + (t>>3);
  int hh = t & 7;
  const float* hr = &h[(long)r*DV];
  float acc = pb[hh];
  #pragma unroll 8
  for(int kk=0; kk<DV; kk++) acc += hr[kk]*pw[kk*HHEADS + hh];
  int b = r >> 10, n = r & 1023;
  float sv, cv;
  __sincosf(acc, &sv, &cv);
  int idx = (b*HHEADS + hh)*NSEQ + n;
  cph[idx] = cv; sph[idx] = sv;
}

// ---------------- MFMA flash attention, phase folded into augmented 96-dim QK ----------------
// grid: 16 bh * 16 qtiles = 256 blocks, 256 threads (4 waves x 16 queries).
// S'[i][j] = 0.5*scale*(q.k + (ci q).(cj k) + (si q).(sj k)); swapped mfma(K~,Q~)
// puts per-lane: query = lane&15, keys = kt*16 + (lane>>4)*4 + r.
__global__ __launch_bounds__(256) void attn_mfma_kernel(
    const __hip_bfloat16* __restrict__ qg, const __hip_bfloat16* __restrict__ kg,
    const __hip_bfloat16* __restrict__ vg,
    const float* __restrict__ cph, const float* __restrict__ sph,
    __hip_bfloat16* __restrict__ msg){
  __shared__ __align__(16) short Ks[64][104];   // 96 used, pad vs bank conflicts
  __shared__ __align__(16) short Vt[32][72];    // transposed V: [d][key]
  __shared__ __align__(16) short Pp[4][16][72]; // per-wave P tile, 64 used
  __shared__ float alS[4][16];
  __shared__ float lS[4][16];
  int bh = blockIdx.x >> 4;
  int qt = blockIdx.x & 15;
  int b = bh >> 3, hh = bh & 7;
  int t = threadIdx.x;
  int lane = t & 63, w = t >> 6;
  int lr = lane & 15, lg = lane >> 4;
  int q0w = qt*64 + w*16;

  // Q~ B-frags (3 k-steps of 32), built in registers, 0.5*scale folded in
  const unsigned short* qrow = (const unsigned short*)qg
      + ((long)(b*NSEQ + q0w + lr))*DV + hh*32 + lg*8;
  short8v qraw = *(const short8v*)qrow;
  float ci = cph[bh*NSEQ + q0w + lr];
  float si = sph[bh*NSEQ + q0w + lr];
  short8v qf0, qf1, qf2;
  #pragma unroll
  for(int i=0;i<8;i++){
    float x = bfbits2f((unsigned short)qraw[i]) * (0.5f*QKSCALE);
    qf0[i] = (short)f2bf(x);
    qf1[i] = (short)f2bf(x*ci);
    qf2[i] = (short)f2bf(x*si);
  }

  float m = -1e30f, l = 0.f;
  f32x4 acc[2] = {};

  int srow = t >> 2, sdc = (t & 3) * 8;
  for(int j0=0; j0<NSEQ; j0+=64){
    __syncthreads();   // prior-tile reads complete
    // ---- stage K (with aug blocks) and V^T ----
    {
      const unsigned short* krow = (const unsigned short*)kg
          + ((long)(b*NSEQ + j0 + srow))*DV + hh*32 + sdc;
      short8v kv = *(const short8v*)krow;
      float cj = cph[bh*NSEQ + j0 + srow];
      float sj = sph[bh*NSEQ + j0 + srow];
      short8v kc, ksn;
      #pragma unroll
      for(int i=0;i<8;i++){
        float x = bfbits2f((unsigned short)kv[i]);
        kc[i]  = (short)f2bf(x*cj);
        ksn[i] = (short)f2bf(x*sj);
      }
      *(short8v*)&Ks[srow][sdc]      = kv;
      *(short8v*)&Ks[srow][32+sdc]   = kc;
      *(short8v*)&Ks[srow][64+sdc]   = ksn;
      const unsigned short* vrow = (const unsigned short*)vg
          + ((long)(b*NSEQ + j0 + srow))*DV + hh*32 + sdc;
      short8v vv = *(const short8v*)vrow;
      #pragma unroll
      for(int i=0;i<8;i++) Vt[sdc+i][srow] = vv[i];
    }
    __syncthreads();   // staging visible
    // ---- S^T tiles: 4 key-subtiles x 3 aug k-steps ----
    f32x4 st[4];
    #pragma unroll
    for(int kt=0; kt<4; kt++){
      short8v a0 = *(const short8v*)&Ks[kt*16+lr][lg*8];
      short8v a1 = *(const short8v*)&Ks[kt*16+lr][32+lg*8];
      short8v a2 = *(const short8v*)&Ks[kt*16+lr][64+lg*8];
      f32x4 z = {0.f,0.f,0.f,0.f};
      z = __builtin_amdgcn_mfma_f32_16x16x32_bf16(a0, qf0, z, 0,0,0);
      z = __builtin_amdgcn_mfma_f32_16x16x32_bf16(a1, qf1, z, 0,0,0);
      z = __builtin_amdgcn_mfma_f32_16x16x32_bf16(a2, qf2, z, 0,0,0);
      st[kt] = z;
    }
    // ---- online softmax (query = lr, 16 keys per lane, 4-lane group) ----
    float pm = -1e30f;
    #pragma unroll
    for(int kt=0; kt<4; kt++)
      #pragma unroll
      for(int r=0; r<4; r++) pm = fmaxf(pm, st[kt][r]);
    pm = fmaxf(pm, __shfl_xor(pm, 16));
    pm = fmaxf(pm, __shfl_xor(pm, 32));
    float mn = fmaxf(m, pm);
    float al = __expf(m - mn);
    float ls = 0.f;
    #pragma unroll
    for(int kt=0; kt<4; kt++){
      float p0 = __expf(st[kt][0]-mn);
      float p1 = __expf(st[kt][1]-mn);
      float p2 = __expf(st[kt][2]-mn);
      float p3 = __expf(st[kt][3]-mn);
      ls += (p0+p1)+(p2+p3);
      unsigned int w0 = (unsigned)f2bf(p0) | ((unsigned)f2bf(p1)<<16);
      unsigned int w1 = (unsigned)f2bf(p2) | ((unsigned)f2bf(p3)<<16);
      unsigned int* pp = (unsigned int*)&Pp[w][lr][kt*16 + lg*4];
      pp[0] = w0; pp[1] = w1;
    }
    ls += __shfl_xor(ls, 16);
    ls += __shfl_xor(ls, 32);
    l = l*al + ls;
    m = mn;
    if(lane < 16) alS[w][lr] = al;
    __syncthreads();   // P/al visible (and lgkmcnt drained)
    // ---- rescale + PV ----
    float alv[4];
    #pragma unroll
    for(int r=0;r<4;r++) alv[r] = alS[w][lg*4+r];
    #pragma unroll
    for(int dt=0; dt<2; dt++)
      #pragma unroll
      for(int r=0;r<4;r++) acc[dt][r] *= alv[r];
    #pragma unroll
    for(int kk=0; kk<2; kk++){
      short8v pa = *(const short8v*)&Pp[w][lr][kk*32 + lg*8];
      short8v vf0 = *(const short8v*)&Vt[lr][kk*32 + lg*8];
      short8v vf1 = *(const short8v*)&Vt[16+lr][kk*32 + lg*8];
      acc[0] = __builtin_amdgcn_mfma_f32_16x16x32_bf16(pa, vf0, acc[0], 0,0,0);
      acc[1] = __builtin_amdgcn_mfma_f32_16x16x32_bf16(pa, vf1, acc[1], 0,0,0);
    }
  }
  if(lane < 16) lS[w][lr] = l;
  __syncthreads();
  float lv[4];
  #pragma unroll
  for(int r=0;r<4;r++) lv[r] = 1.f/lS[w][lg*4+r];
  #pragma unroll
  for(int dt=0; dt<2; dt++)
    #pragma unroll
    for(int r=0;r<4;r++){
      int row = q0w + lg*4 + r;
      msg[((long)(b*NSEQ + row))*DV + hh*32 + dt*16 + lr] =
          __float2bfloat16(acc[dt][r]*lv[r]);
    }
}

// ---------------- mean pool (2 stages) ----------------
__global__ __launch_bounds__(256) void pool1_kernel(const float* __restrict__ x, float* __restrict__ part){
  int t = threadIdx.x;
  int b = blockIdx.x >> 4, c = blockIdx.x & 15;
  long base = (long)(b*NSEQ + c*64)*DV + t;
  float acc = 0.f;
  #pragma unroll 4
  for(int i=0;i<64;i++) acc += x[base + (long)i*DV];
  part[blockIdx.x*DV + t] = acc;
}

__global__ __launch_bounds__(256) void pool2_kernel(const float* __restrict__ part, float* __restrict__ pooled){
  int t = threadIdx.x, b = blockIdx.x;
  float acc = 0.f;
  #pragma unroll
  for(int c=0;c<16;c++) acc += part[(b*16+c)*DV + t];
  pooled[b*DV + t] = acc * (1.f/ (float)NSEQ);
}

// ---------------- head ----------------
__global__ __launch_bounds__(256) void head_kernel(
    const float* __restrict__ pooled, const float* __restrict__ W,
    const float* __restrict__ hb, float* __restrict__ out){
  int vcol = blockIdx.x*256 + threadIdx.x;
  float a0 = 0.f, a1 = 0.f;
  #pragma unroll 8
  for(int d=0; d<DV; d++){
    float w = W[(long)d*VV + vcol];
    a0 += pooled[d]*w;
    a1 += pooled[DV+d]*w;
  }
  float bb = hb[vcol];
  out[vcol] = a0 + bb;
  out[VV + vcol] = a1 + bb;
}

extern "C" void kernel_launch(void* const* d_in, const int* in_sizes, int n_in,
                              void* d_out, int out_size, void* d_ws, size_t ws_size,
                              hipStream_t stream){
  const int*   ids   = (const int*)  d_in[0];
  const float* tok   = (const float*)d_in[1];
  const float* pos   = (const float*)d_in[2];
  const float* en_g  = (const float*)d_in[3];
  const float* en_b  = (const float*)d_in[4];
  const float* Wq    = (const float*)d_in[7];
  const float* Wk    = (const float*)d_in[8];
  const float* Wv    = (const float*)d_in[9];
  const float* Wo    = (const float*)d_in[10];
  const float* pp_w  = (const float*)d_in[11];
  const float* pp_b  = (const float*)d_in[12];
  const float* f1_w  = (const float*)d_in[13];
  const float* f1_b  = (const float*)d_in[14];
  const float* f2_w  = (const float*)d_in[15];
  const float* f2_b  = (const float*)d_in[16];
  const float* ln1_g = (const float*)d_in[17];
  const float* ln1_b = (const float*)d_in[18];
  const float* ln2_g = (const float*)d_in[19];
  const float* ln2_b = (const float*)d_in[20];
  const float* on_g  = (const float*)d_in[23];
  const float* on_b  = (const float*)d_in[24];
  const float* head_w= (const float*)d_in[25];
  const float* head_b= (const float*)d_in[26];
  float* out = (float*)d_out;

  char* wsb = (char*)d_ws;
  float* h    = (float*)(wsb);                               // 2 MB f32
  float* s2   = (float*)(wsb + (2u<<20));                    // 2 MB f32
  __hip_bfloat16* qbh = (__hip_bfloat16*)(wsb + (4u<<20));   // 1 MB bf16
  __hip_bfloat16* kbh = (__hip_bfloat16*)(wsb + (5u<<20));   // 1 MB bf16
  __hip_bfloat16* vbh = (__hip_bfloat16*)(wsb + (6u<<20));   // 1 MB bf16
  __hip_bfloat16* ff  = (__hip_bfloat16*)(wsb + (4u<<20));   // 4 MB bf16 (FF phase, overlays qkv)
  __hip_bfloat16* hb  = (__hip_bfloat16*)(wsb + (10u<<20));  // 1 MB
  __hip_bfloat16* msgb= (__hip_bfloat16*)(wsb + (11u<<20));  // 1 MB
  float* cphb = (float*)(wsb + (12u<<20));                   // 64 KB
  float* sphb = cphb + 16384;
  float* part = sphb + 16384;
  float* pooled = part + 8192;
  __hip_bfloat16* wt = (__hip_bfloat16*)(wsb + (12u<<20) + (256u<<10));
  __hip_bfloat16* wqt = wt;
  __hip_bfloat16* wkt = wt + 2*65536;
  __hip_bfloat16* wvt = wt + 4*65536;
  __hip_bfloat16* wot = wt + 6*65536;
  __hip_bfloat16* f1t = wt + 8*65536;
  __hip_bfloat16* f2t = f1t + 2*262144;

  transpose_cvt_all<<<1536, 256, 0, stream>>>(Wq, Wk, Wv, Wo, f1_w, f2_w, wt);
  embed_ln_kernel<<<512, 256, 0, stream>>>(ids, tok, pos, en_g, en_b, h, hb);

  dim3 g_dd(32, 4);
  dim3 g_df(32, 16);
  for(int tt=0; tt<2; tt++){
    for(int l=0; l<2; l++){
      mfma_gemm<0,1><<<g_dd, 256, 0, stream>>>(hb, wqt + l*65536, nullptr, qbh, 2048, 256, 256);
      mfma_gemm<0,1><<<g_dd, 256, 0, stream>>>(hb, wkt + l*65536, nullptr, kbh, 2048, 256, 256);
      mfma_gemm<0,1><<<g_dd, 256, 0, stream>>>(hb, wvt + l*65536, nullptr, vbh, 2048, 256, 256);
      phase_kernel<<<64, 256, 0, stream>>>(h, pp_w + l*(DV*HHEADS), pp_b + l*HHEADS, cphb, sphb);
      attn_mfma_kernel<<<256, 256, 0, stream>>>(qbh, kbh, vbh, cphb, sphb, msgb);
      mfma_gemm<0,0><<<g_dd, 256, 0, stream>>>(msgb, wot + l*65536, nullptr, s2, 2048, 256, 256);
      ln_res_kernel<<<512, 256, 0, stream>>>(s2, h, h, hb, ln1_g + l*DV, ln1_b + l*DV);
      mfma_gemm<1,1><<<g_df, 256, 0, stream>>>(hb, f1t + l*262144, f1_b + l*1024, ff, 2048, 1024, 256);
      mfma_gemm<0,0><<<g_dd, 256, 0, stream>>>(ff, f2t + l*262144, f2_b + l*DV, s2, 2048, 256, 1024);
      ln_res_kernel<<<512, 256, 0, stream>>>(s2, h, h, hb, ln2_g + l*DV, ln2_b + l*DV);
    }
  }
  ln_res_kernel<<<512, 256, 0, stream>>>(h, nullptr, s2, nullptr, on_g, on_b);
  pool1_kernel<<<32, 256, 0, stream>>>(s2, part);
  pool2_kernel<<<2, 256, 0, stream>>>(part, pooled);
  head_kernel<<<125, 256, 0, stream>>>(pooled, head_w, head_b, out);
}

// Round 4
// 268.963 us; speedup vs baseline: 3.7494x; 1.3429x over previous
//
#include <hip/hip_runtime.h>
#include <hip/hip_bf16.h>
#include <math.h>

#define DV 256
#define NSEQ 1024
#define HHEADS 8
#define VV 32000
#define QKSCALE 0.17677669529663687f  // 1/sqrt(32)

typedef __attribute__((ext_vector_type(8))) short short8v;
typedef __attribute__((ext_vector_type(4))) float f32x4;

__device__ __forceinline__ unsigned short f2bf(float f){
  __hip_bfloat16 b = __float2bfloat16(f);
  return *reinterpret_cast<unsigned short*>(&b);
}
__device__ __forceinline__ float bfbits2f(unsigned short u){
  unsigned int x = ((unsigned int)u) << 16;
  return __uint_as_float(x);
}

// ---------------- weight transpose + f32->bf16 convert ----------------
// dst (bf16): wqkvp 2x[832][256] | wot 2x[256][256] | f1t 2x[1024][256] | f2t 2x[256][1024]
#define OFF_WQKVP 0
#define OFF_WOT   425984
#define OFF_F1T   557056
#define OFF_F2T   1081344
__global__ __launch_bounds__(256) void transpose_cvt_all(
    const float* __restrict__ Wq, const float* __restrict__ Wk,
    const float* __restrict__ Wv, const float* __restrict__ Wo,
    const float* __restrict__ ppw, const float* __restrict__ f1w,
    const float* __restrict__ f2w, __hip_bfloat16* __restrict__ dst){
  __shared__ float sh[32][33];
  int bid = blockIdx.x;
  int t = threadIdx.x;
  if(bid >= 512 && bid < 528){
    // phase weight rows 768..831 of wqkvp[l] (768..775 = pp_w^T, rest zero)
    int idx = bid - 512;
    int l = idx >> 3, k0 = (idx & 7) * 32;
    int rowo = t >> 2;                 // 0..63
    int kbase = k0 + (t & 3) * 8;
    unsigned short vals[8];
    if(rowo < 8){
      int hh = rowo;
      #pragma unroll
      for(int i=0;i<8;i++) vals[i] = f2bf(ppw[(long)l*2048 + (kbase+i)*HHEADS + hh]);
    } else {
      #pragma unroll
      for(int i=0;i<8;i++) vals[i] = 0;
    }
    unsigned short* d = (unsigned short*)dst + (long)l*212992 + (768+rowo)*256 + kbase;
    #pragma unroll
    for(int i=0;i<8;i++) d[i] = vals[i];
    return;
  }
  const float* src; __hip_bfloat16* d; int K, N, tile;
  if(bid < 384){
    int l = bid / 192, rem = bid % 192, mat = rem >> 6; tile = rem & 63;
    src = (mat==0 ? Wq : (mat==1 ? Wk : Wv)) + l*65536;
    d = dst + (long)l*212992 + mat*65536;
    K = 256; N = 256;
  } else if(bid < 512){
    int b2 = bid - 384; int l = b2 >> 6; tile = b2 & 63;
    src = Wo + l*65536; d = dst + OFF_WOT + l*65536; K = 256; N = 256;
  } else if(bid < 1040){
    int b2 = bid - 528; int l = b2 >> 8; tile = b2 & 255;
    src = f1w + l*262144; d = dst + OFF_F1T + l*262144; K = 256; N = 1024;
  } else {
    int b2 = bid - 1040; int l = b2 >> 8; tile = b2 & 255;
    src = f2w + l*262144; d = dst + OFF_F2T + l*262144; K = 1024; N = 256;
  }
  int ntn = N >> 5;
  int tk = tile / ntn, tn = tile - tk*ntn;
  int k0 = tk*32, n0 = tn*32;
  {
    int rr = t >> 3, cc = (t & 7) * 4;
    float4 v = *(const float4*)&src[(long)(k0+rr)*N + n0 + cc];
    sh[rr][cc]=v.x; sh[rr][cc+1]=v.y; sh[rr][cc+2]=v.z; sh[rr][cc+3]=v.w;
  }
  __syncthreads();
  int nn = t >> 3, kk = (t & 7) * 4;
  ushort4 o;
  o.x = f2bf(sh[kk+0][nn]);
  o.y = f2bf(sh[kk+1][nn]);
  o.z = f2bf(sh[kk+2][nn]);
  o.w = f2bf(sh[kk+3][nn]);
  *(ushort4*)&((unsigned short*)d)[(long)(n0+nn)*K + k0 + kk] = o;
}

// ---------------- embedding + LayerNorm ----------------
__global__ __launch_bounds__(256) void embed_ln_kernel(
    const int* __restrict__ ids, const float* __restrict__ tok, const float* __restrict__ pos,
    const float* __restrict__ g, const float* __restrict__ bt,
    float* __restrict__ h, __hip_bfloat16* __restrict__ hb){
  int t = threadIdx.x;
  int lane = t & 63;
  int row = blockIdx.x*4 + (t >> 6);
  int n = row & (NSEQ-1);
  int id = ids[row];
  float4 vv = ((const float4*)tok)[(long)id*64 + lane];
  float4 pv = ((const float4*)pos)[n*64 + lane];
  vv.x += pv.x; vv.y += pv.y; vv.z += pv.z; vv.w += pv.w;
  float s  = vv.x+vv.y+vv.z+vv.w;
  float s2 = vv.x*vv.x+vv.y*vv.y+vv.z*vv.z+vv.w*vv.w;
  #pragma unroll
  for(int off=1; off<64; off<<=1){ s += __shfl_xor(s, off); s2 += __shfl_xor(s2, off); }
  float mean = s*(1.f/DV);
  float var = fmaxf(s2*(1.f/DV) - mean*mean, 0.f);
  float inv = rsqrtf(var + 1e-5f);
  float4 gv = ((const float4*)g)[lane];
  float4 bv = ((const float4*)bt)[lane];
  float4 o;
  o.x=(vv.x-mean)*inv*gv.x+bv.x; o.y=(vv.y-mean)*inv*gv.y+bv.y;
  o.z=(vv.z-mean)*inv*gv.z+bv.z; o.w=(vv.w-mean)*inv*gv.w+bv.w;
  ((float4*)h)[row*64 + lane] = o;
  ushort4 ob; ob.x=f2bf(o.x); ob.y=f2bf(o.y); ob.z=f2bf(o.z); ob.w=f2bf(o.w);
  *(ushort4*)&hb[row*DV + lane*4] = ob;
}

// ---------------- (residual +) LayerNorm ----------------
__global__ __launch_bounds__(256) void ln_res_kernel(
    const float* __restrict__ x, const float* __restrict__ r,
    float* __restrict__ out, __hip_bfloat16* __restrict__ outb,
    const float* __restrict__ g, const float* __restrict__ bt){
  int t = threadIdx.x;
  int lane = t & 63;
  int row = blockIdx.x*4 + (t >> 6);
  float4 vv = ((const float4*)x)[row*64 + lane];
  if(r){
    float4 rv = ((const float4*)r)[row*64 + lane];
    vv.x += rv.x; vv.y += rv.y; vv.z += rv.z; vv.w += rv.w;
  }
  float s  = vv.x+vv.y+vv.z+vv.w;
  float s2 = vv.x*vv.x+vv.y*vv.y+vv.z*vv.z+vv.w*vv.w;
  #pragma unroll
  for(int off=1; off<64; off<<=1){ s += __shfl_xor(s, off); s2 += __shfl_xor(s2, off); }
  float mean = s*(1.f/DV);
  float var = fmaxf(s2*(1.f/DV) - mean*mean, 0.f);
  float inv = rsqrtf(var + 1e-5f);
  float4 gv = ((const float4*)g)[lane];
  float4 bv = ((const float4*)bt)[lane];
  float4 o;
  o.x=(vv.x-mean)*inv*gv.x+bv.x; o.y=(vv.y-mean)*inv*gv.y+bv.y;
  o.z=(vv.z-mean)*inv*gv.z+bv.z; o.w=(vv.w-mean)*inv*gv.w+bv.w;
  ((float4*)out)[row*64 + lane] = o;
  if(outb){
    ushort4 ob; ob.x=f2bf(o.x); ob.y=f2bf(o.y); ob.z=f2bf(o.z); ob.w=f2bf(o.w);
    *(ushort4*)&outb[row*DV + lane*4] = ob;
  }
}

// ---------------- generic bf16 MFMA GEMM: C[M,N] = A[M,K] @ Bt[N,K]^T ----------------
// Tile BM x BN (BM=WM*FM*16, BN=WN*FN*16), 4 waves, BK=128 chunks.
// LDS stride 136 shorts: 4-bank shift/row -> 2-way (free) frag reads, uniform stage writes.
// PHASE: the tile at tn==N-64 computes sincos(acc + pb) into cph/sph instead of C.
template<int WM, int WN, int FM, int FN, int ACT, int OUT_BF16, int PHASE>
__global__ __launch_bounds__(256) void mfma_gemm(
    const __hip_bfloat16* __restrict__ A, const __hip_bfloat16* __restrict__ Bt,
    const float* __restrict__ bias, void* __restrict__ Cout,
    int M, int N, int K, int ldc,
    const float* __restrict__ pb, float* __restrict__ cph, float* __restrict__ sph){
  constexpr int BM = WM*FM*16;
  constexpr int BN = WN*FN*16;
  constexpr int TPRA = 256/BM;      // threads per A-row
  constexpr int JA = 16/TPRA;       // short8v chunks per thread (BK=128)
  __shared__ short As[BM][136];
  __shared__ short Bs[BN][136];
  int tm = blockIdx.x*BM, tn = blockIdx.y*BN;
  int t = threadIdx.x;
  int lane = t & 63, w = t >> 6;
  int wm = w / WN, wn = w % WN;
  int lr = lane & 15, lg = lane >> 4;
  f32x4 acc[FM][FN] = {};
  const short* gA = (const short*)A;
  const short* gB = (const short*)Bt;
  int ra = t / TPRA, ca = t % TPRA;
  int rb = t >> 2,  cb = t & 3;
  for(int k0=0; k0<K; k0+=128){
    __syncthreads();
    {
      const short* pa = &gA[(long)(tm+ra)*K + k0];
      #pragma unroll
      for(int j=0;j<JA;j++){
        int c8 = ca + TPRA*j;
        *(short8v*)&As[ra][c8*8] = *(const short8v*)&pa[c8*8];
      }
      const short* pbp = &gB[(long)(tn+rb)*K + k0];
      #pragma unroll
      for(int j=0;j<4;j++){
        int c8 = cb + 4*j;
        *(short8v*)&Bs[rb][c8*8] = *(const short8v*)&pbp[c8*8];
      }
    }
    __syncthreads();
    #pragma unroll
    for(int ks=0; ks<4; ks++){
      short8v af[FM], bf[FN];
      #pragma unroll
      for(int i=0;i<FM;i++) af[i] = *(const short8v*)&As[wm*FM*16 + i*16 + lr][ks*32 + lg*8];
      #pragma unroll
      for(int j=0;j<FN;j++) bf[j] = *(const short8v*)&Bs[wn*FN*16 + j*16 + lr][ks*32 + lg*8];
      #pragma unroll
      for(int i=0;i<FM;i++)
        #pragma unroll
        for(int j=0;j<FN;j++)
          acc[i][j] = __builtin_amdgcn_mfma_f32_16x16x32_bf16(af[i], bf[j], acc[i][j], 0,0,0);
    }
  }
  if(PHASE && tn >= N - 64){
    // phase tile: cols (rel) 0..7 are heads; acc holds ph - pb
    #pragma unroll
    for(int fn=0; fn<FN; fn++){
      int colr = wn*FN*16 + fn*16 + lr;
      if(colr < 8){
        float bb = pb[colr];
        #pragma unroll
        for(int fm=0; fm<FM; fm++){
          int row0 = tm + wm*FM*16 + fm*16 + lg*4;
          #pragma unroll
          for(int r2=0; r2<4; r2++){
            float ph = acc[fm][fn][r2] + bb;
            float sv, cv;
            __sincosf(ph, &sv, &cv);
            int row = row0 + r2;
            int b = row >> 10, n = row & 1023;
            int idx = (b*HHEADS + colr)*NSEQ + n;
            cph[idx] = cv; sph[idx] = sv;
          }
        }
      }
    }
    return;
  }
  #pragma unroll
  for(int fn=0; fn<FN; fn++){
    int col = tn + wn*FN*16 + fn*16 + lr;
    float bs = bias ? bias[col] : 0.f;
    #pragma unroll
    for(int fm=0; fm<FM; fm++){
      int row0 = tm + wm*FM*16 + fm*16 + lg*4;
      #pragma unroll
      for(int r2=0; r2<4; r2++){
        float xx = acc[fm][fn][r2] + bs;
        if(ACT == 1) xx = 0.5f*xx*(1.f + erff(xx*0.70710678118654752f));
        long idx = (long)(row0+r2)*ldc + col;
        if(OUT_BF16) ((__hip_bfloat16*)Cout)[idx] = __float2bfloat16(xx);
        else         ((float*)Cout)[idx] = xx;
      }
    }
  }
}

// ---------------- MFMA flash attention (augmented 96-dim QK), qkv fused buffer ----------------
// qkv: [2048][768] bf16, cols 0-255=Q, 256-511=K, 512-767=V.
__global__ __launch_bounds__(256) void attn_mfma_kernel(
    const __hip_bfloat16* __restrict__ qkv,
    const float* __restrict__ cph, const float* __restrict__ sph,
    __hip_bfloat16* __restrict__ msg){
  __shared__ __align__(16) short Ks[64][104];
  __shared__ __align__(16) short Vt[32][72];
  __shared__ __align__(16) short Pp[4][16][72];
  __shared__ float alS[4][16];
  __shared__ float lS[4][16];
  int bh = blockIdx.x >> 4;
  int qt = blockIdx.x & 15;
  int b = bh >> 3, hh = bh & 7;
  int t = threadIdx.x;
  int lane = t & 63, w = t >> 6;
  int lr = lane & 15, lg = lane >> 4;
  int q0w = qt*64 + w*16;

  const unsigned short* qrow = (const unsigned short*)qkv
      + ((long)(b*NSEQ + q0w + lr))*768 + hh*32 + lg*8;
  short8v qraw = *(const short8v*)qrow;
  float ci = cph[bh*NSEQ + q0w + lr];
  float si = sph[bh*NSEQ + q0w + lr];
  short8v qf0, qf1, qf2;
  #pragma unroll
  for(int i=0;i<8;i++){
    float x = bfbits2f((unsigned short)qraw[i]) * (0.5f*QKSCALE);
    qf0[i] = (short)f2bf(x);
    qf1[i] = (short)f2bf(x*ci);
    qf2[i] = (short)f2bf(x*si);
  }

  float m = -1e30f, l = 0.f;
  f32x4 acc[2] = {};

  int srow = t >> 2, sdc = (t & 3) * 8;
  for(int j0=0; j0<NSEQ; j0+=64){
    __syncthreads();
    {
      const unsigned short* krow = (const unsigned short*)qkv
          + ((long)(b*NSEQ + j0 + srow))*768 + 256 + hh*32 + sdc;
      short8v kv = *(const short8v*)krow;
      float cj = cph[bh*NSEQ + j0 + srow];
      float sj = sph[bh*NSEQ + j0 + srow];
      short8v kc, ksn;
      #pragma unroll
      for(int i=0;i<8;i++){
        float x = bfbits2f((unsigned short)kv[i]);
        kc[i]  = (short)f2bf(x*cj);
        ksn[i] = (short)f2bf(x*sj);
      }
      *(short8v*)&Ks[srow][sdc]      = kv;
      *(short8v*)&Ks[srow][32+sdc]   = kc;
      *(short8v*)&Ks[srow][64+sdc]   = ksn;
      const unsigned short* vrow = (const unsigned short*)qkv
          + ((long)(b*NSEQ + j0 + srow))*768 + 512 + hh*32 + sdc;
      short8v vv = *(const short8v*)vrow;
      #pragma unroll
      for(int i=0;i<8;i++) Vt[sdc+i][srow] = vv[i];
    }
    __syncthreads();
    f32x4 st[4];
    #pragma unroll
    for(int kt=0; kt<4; kt++){
      short8v a0 = *(const short8v*)&Ks[kt*16+lr][lg*8];
      short8v a1 = *(const short8v*)&Ks[kt*16+lr][32+lg*8];
      short8v a2 = *(const short8v*)&Ks[kt*16+lr][64+lg*8];
      f32x4 z = {0.f,0.f,0.f,0.f};
      z = __builtin_amdgcn_mfma_f32_16x16x32_bf16(a0, qf0, z, 0,0,0);
      z = __builtin_amdgcn_mfma_f32_16x16x32_bf16(a1, qf1, z, 0,0,0);
      z = __builtin_amdgcn_mfma_f32_16x16x32_bf16(a2, qf2, z, 0,0,0);
      st[kt] = z;
    }
    float pm = -1e30f;
    #pragma unroll
    for(int kt=0; kt<4; kt++)
      #pragma unroll
      for(int r=0; r<4; r++) pm = fmaxf(pm, st[kt][r]);
    pm = fmaxf(pm, __shfl_xor(pm, 16));
    pm = fmaxf(pm, __shfl_xor(pm, 32));
    float mn = fmaxf(m, pm);
    float al = __expf(m - mn);
    float ls = 0.f;
    #pragma unroll
    for(int kt=0; kt<4; kt++){
      float p0 = __expf(st[kt][0]-mn);
      float p1 = __expf(st[kt][1]-mn);
      float p2 = __expf(st[kt][2]-mn);
      float p3 = __expf(st[kt][3]-mn);
      ls += (p0+p1)+(p2+p3);
      unsigned int w0 = (unsigned)f2bf(p0) | ((unsigned)f2bf(p1)<<16);
      unsigned int w1 = (unsigned)f2bf(p2) | ((unsigned)f2bf(p3)<<16);
      unsigned int* pp = (unsigned int*)&Pp[w][lr][kt*16 + lg*4];
      pp[0] = w0; pp[1] = w1;
    }
    ls += __shfl_xor(ls, 16);
    ls += __shfl_xor(ls, 32);
    l = l*al + ls;
    m = mn;
    if(lane < 16) alS[w][lr] = al;
    __syncthreads();
    float alv[4];
    #pragma unroll
    for(int r=0;r<4;r++) alv[r] = alS[w][lg*4+r];
    #pragma unroll
    for(int dt=0; dt<2; dt++)
      #pragma unroll
      for(int r=0;r<4;r++) acc[dt][r] *= alv[r];
    #pragma unroll
    for(int kk=0; kk<2; kk++){
      short8v pa = *(const short8v*)&Pp[w][lr][kk*32 + lg*8];
      short8v vf0 = *(const short8v*)&Vt[lr][kk*32 + lg*8];
      short8v vf1 = *(const short8v*)&Vt[16+lr][kk*32 + lg*8];
      acc[0] = __builtin_amdgcn_mfma_f32_16x16x32_bf16(pa, vf0, acc[0], 0,0,0);
      acc[1] = __builtin_amdgcn_mfma_f32_16x16x32_bf16(pa, vf1, acc[1], 0,0,0);
    }
  }
  if(lane < 16) lS[w][lr] = l;
  __syncthreads();
  float lv[4];
  #pragma unroll
  for(int r=0;r<4;r++) lv[r] = 1.f/lS[w][lg*4+r];
  #pragma unroll
  for(int dt=0; dt<2; dt++)
    #pragma unroll
    for(int r=0;r<4;r++){
      int row = q0w + lg*4 + r;
      msg[((long)(b*NSEQ + row))*DV + hh*32 + dt*16 + lr] =
          __float2bfloat16(acc[dt][r]*lv[r]);
    }
}

// ---------------- mean pool (2 stages) ----------------
__global__ __launch_bounds__(256) void pool1_kernel(const float* __restrict__ x, float* __restrict__ part){
  int t = threadIdx.x;
  int b = blockIdx.x >> 4, c = blockIdx.x & 15;
  long base = (long)(b*NSEQ + c*64)*DV + t;
  float acc = 0.f;
  #pragma unroll 4
  for(int i=0;i<64;i++) acc += x[base + (long)i*DV];
  part[blockIdx.x*DV + t] = acc;
}

__global__ __launch_bounds__(256) void pool2_kernel(const float* __restrict__ part, float* __restrict__ pooled){
  int t = threadIdx.x, b = blockIdx.x;
  float acc = 0.f;
  #pragma unroll
  for(int c=0;c<16;c++) acc += part[(b*16+c)*DV + t];
  pooled[b*DV + t] = acc * (1.f/ (float)NSEQ);
}

// ---------------- head ----------------
__global__ __launch_bounds__(256) void head_kernel(
    const float* __restrict__ pooled, const float* __restrict__ W,
    const float* __restrict__ hb, float* __restrict__ out){
  int vcol = blockIdx.x*256 + threadIdx.x;
  float a0 = 0.f, a1 = 0.f;
  #pragma unroll 8
  for(int d=0; d<DV; d++){
    float w = W[(long)d*VV + vcol];
    a0 += pooled[d]*w;
    a1 += pooled[DV+d]*w;
  }
  float bb = hb[vcol];
  out[vcol] = a0 + bb;
  out[VV + vcol] = a1 + bb;
}

extern "C" void kernel_launch(void* const* d_in, const int* in_sizes, int n_in,
                              void* d_out, int out_size, void* d_ws, size_t ws_size,
                              hipStream_t stream){
  const int*   ids   = (const int*)  d_in[0];
  const float* tok   = (const float*)d_in[1];
  const float* pos   = (const float*)d_in[2];
  const float* en_g  = (const float*)d_in[3];
  const float* en_b  = (const float*)d_in[4];
  const float* Wq    = (const float*)d_in[7];
  const float* Wk    = (const float*)d_in[8];
  const float* Wv    = (const float*)d_in[9];
  const float* Wo    = (const float*)d_in[10];
  const float* pp_w  = (const float*)d_in[11];
  const float* pp_b  = (const float*)d_in[12];
  const float* f1_w  = (const float*)d_in[13];
  const float* f1_b  = (const float*)d_in[14];
  const float* f2_w  = (const float*)d_in[15];
  const float* f2_b  = (const float*)d_in[16];
  const float* ln1_g = (const float*)d_in[17];
  const float* ln1_b = (const float*)d_in[18];
  const float* ln2_g = (const float*)d_in[19];
  const float* ln2_b = (const float*)d_in[20];
  const float* on_g  = (const float*)d_in[23];
  const float* on_b  = (const float*)d_in[24];
  const float* head_w= (const float*)d_in[25];
  const float* head_b= (const float*)d_in[26];
  float* out = (float*)d_out;

  char* wsb = (char*)d_ws;
  float* h    = (float*)(wsb);                               // 2 MB f32
  float* s2   = (float*)(wsb + (2u<<20));                    // 2 MB f32
  __hip_bfloat16* qkv = (__hip_bfloat16*)(wsb + (4u<<20));   // 3 MB bf16 (2048x768)
  __hip_bfloat16* ff  = (__hip_bfloat16*)(wsb + (4u<<20));   // 4 MB bf16 (FF phase, overlays qkv)
  __hip_bfloat16* hb  = (__hip_bfloat16*)(wsb + (8u<<20));   // 1 MB
  __hip_bfloat16* msgb= (__hip_bfloat16*)(wsb + (9u<<20));   // 1 MB
  float* cphb = (float*)(wsb + (10u<<20));                   // 64 KB
  float* sphb = cphb + 16384;                                // 64 KB
  float* part = sphb + 16384;                                // 32 KB
  float* pooled = part + 8192;                               // 2 KB
  __hip_bfloat16* wt = (__hip_bfloat16*)(wsb + (10u<<20) + (256u<<10)); // ~3.1 MB
  __hip_bfloat16* wqkvp = wt + OFF_WQKVP;
  __hip_bfloat16* wot   = wt + OFF_WOT;
  __hip_bfloat16* f1t   = wt + OFF_F1T;
  __hip_bfloat16* f2t   = wt + OFF_F2T;

  transpose_cvt_all<<<1552, 256, 0, stream>>>(Wq, Wk, Wv, Wo, pp_w, f1_w, f2_w, wt);
  embed_ln_kernel<<<512, 256, 0, stream>>>(ids, tok, pos, en_g, en_b, h, hb);

  for(int tt=0; tt<2; tt++){
    for(int l=0; l<2; l++){
      // fused QKV + phase projection
      mfma_gemm<2,2,2,2, 0,1,1><<<dim3(32,13), 256, 0, stream>>>(
          hb, wqkvp + (long)l*212992, nullptr, qkv, 2048, 832, 256, 768,
          pp_b + l*HHEADS, cphb, sphb);
      attn_mfma_kernel<<<256, 256, 0, stream>>>(qkv, cphb, sphb, msgb);
      mfma_gemm<1,4,2,1, 0,0,0><<<dim3(64,4), 256, 0, stream>>>(
          msgb, wot + l*65536, nullptr, s2, 2048, 256, 256, 256,
          nullptr, nullptr, nullptr);
      ln_res_kernel<<<512, 256, 0, stream>>>(s2, h, h, hb, ln1_g + l*DV, ln1_b + l*DV);
      mfma_gemm<2,2,2,2, 1,1,0><<<dim3(32,16), 256, 0, stream>>>(
          hb, f1t + l*262144, f1_b + l*1024, ff, 2048, 1024, 256, 1024,
          nullptr, nullptr, nullptr);
      mfma_gemm<1,4,2,1, 0,0,0><<<dim3(64,4), 256, 0, stream>>>(
          ff, f2t + l*262144, f2_b + l*DV, s2, 2048, 256, 1024, 256,
          nullptr, nullptr, nullptr);
      ln_res_kernel<<<512, 256, 0, stream>>>(s2, h, h, hb, ln2_g + l*DV, ln2_b + l*DV);
    }
  }
  ln_res_kernel<<<512, 256, 0, stream>>>(h, nullptr, s2, nullptr, on_g, on_b);
  pool1_kernel<<<32, 256, 0, stream>>>(s2, part);
  pool2_kernel<<<2, 256, 0, stream>>>(part, pooled);
  head_kernel<<<125, 256, 0, stream>>>(pooled, head_w, head_b, out);
}